// Round 4
// baseline (461.787 us; speedup 1.0000x reference)
//
#include <hip/hip_runtime.h>

// HighQualityNSN2NLoss — B=16, H=W=768, fp32, scalar out. x_ip1 unused.
//
// R4 changes (pass1 was latency-bound: VALUBusy 35%, HBM 11%, occ 27%):
//  - HSEG 12 -> 6: 6144 waves (1536 blocks = exactly 6/CU) for TLP.
//  - software-pipelined row loop: rows prefetched 2 ahead of use.
//  - histogram flush: plain coalesced stores to per-block parts + reduce
//    kernel (was 1.6M global atomics into 32 cache lines at block end).
//    Direct-atomic fallback retained if ws is too small for parts.

#define HH 768
#define WW 768
#define BB 16
#define HWSZ (HH * WW)
#define NPXD ((double)BB * (double)HWSZ)

#define NB 1024
#define NHIST (2 * NB)

#define STRIPS 3           // 256-wide column strips
#define HSEG 6             // rows per wave-job
#define NSEG (HH / HSEG)   // 128
#define NJOBS (STRIPS * NSEG * BB)  // 6144
#define NBLK1 (NJOBS / 4)           // 1536 blocks (4 waves each) = 6/CU

#define FBBUF 128          // per-wave fb buffer

__device__ __forceinline__ float wredf(float v) {
#pragma unroll
  for (int o = 32; o > 0; o >>= 1) v += __shfl_down(v, o, 64);
  return v;
}
__device__ __forceinline__ unsigned wredu(unsigned v) {
#pragma unroll
  for (int o = 32; o > 0; o >>= 1) v += __shfl_down(v, o, 64);
  return v;
}

struct Row {
  float f[4];
  float l, r;
};

__device__ __forceinline__ Row load_row(const float* __restrict__ p, int y,
                                        int xl, int x0, int lane) {
  Row r;
  if (y < 0 || y >= HH) {
    r.f[0] = r.f[1] = r.f[2] = r.f[3] = 0.f;
    r.l = 0.f;
    r.r = 0.f;
    return r;
  }
  const float4 v = *(const float4*)(p + (size_t)y * WW + xl);
  r.f[0] = v.x; r.f[1] = v.y; r.f[2] = v.z; r.f[3] = v.w;
  float left = __shfl_up(v.w, 1, 64);
  float right = __shfl_down(v.x, 1, 64);
  if (lane == 0) left = (x0 > 0) ? p[(size_t)y * WW + x0 - 1] : 0.f;
  if (lane == 63) right = (x0 + 256 < WW) ? p[(size_t)y * WW + x0 + 256] : 0.f;
  r.l = left;
  r.r = right;
  return r;
}

__device__ __forceinline__ Row zero_row() {
  Row r;
  r.f[0] = r.f[1] = r.f[2] = r.f[3] = 0.f;
  r.l = 0.f; r.r = 0.f;
  return r;
}

#define LNB(row, j) ((j) == 0 ? (row).l : (row).f[(j)-1])
#define RNB(row, j) ((j) == 3 ? (row).r : (row).f[(j) + 1])

// accs: 0 rc, 1 sum_xi_body, 2 sum_yp_body, 3 edge_x, 4 edge_y,
//       5 tex, 6 hf, 7 ic, 8 lf, 9 mid, 10 syn
// cnts: 0 body, 1 tex, 2 flat, 3 fb (append counter)

__global__ __launch_bounds__(256, 5) void pass1_kernel(
    const float* __restrict__ yp, const float* __restrict__ xi,
    const float* __restrict__ wt, double* __restrict__ accs,
    unsigned* __restrict__ cnts, unsigned* __restrict__ fb_list, int fb_cap,
    unsigned* __restrict__ hist_final, unsigned* __restrict__ hist_parts,
    int use_parts) {
  __shared__ unsigned s_hist[NHIST];
  __shared__ unsigned s_fb[4][FBBUF];
  __shared__ unsigned s_fbn[4];
  __shared__ float s_redf[4][8];
  __shared__ unsigned s_redc[4][3];

  const int tid = threadIdx.x;
  const int lane = tid & 63;
  const int wv = tid >> 6;
  const unsigned long long lmask_lt = (1ull << lane) - 1ull;

  for (int i = tid; i < NHIST; i += 256) s_hist[i] = 0u;
  if (lane == 0) s_fbn[wv] = 0u;
  __syncthreads();

  const int job = blockIdx.x * 4 + wv;
  const int s = job % STRIPS;
  const int seg = (job / STRIPS) % NSEG;
  const int b = job / (STRIPS * NSEG);
  const int x0 = s * 256;
  const int y0 = seg * HSEG;
  const int xl = x0 + lane * 4;
  const size_t base = (size_t)b * HWSZ;
  const float* ypb = yp + base;
  const float* xib = xi + base;
  const float* wtb = wt + base;

  float a_rc = 0.f, a_sxi = 0.f, a_syp = 0.f, a_ex = 0.f, a_ey = 0.f;
  float a_tex = 0.f, a_hf = 0.f, a_ic = 0.f;
  unsigned c_body = 0u, c_tex = 0u, c_flat = 0u;

  // software pipeline: rows held for y-1, y, y+1; prefetch y+2 each iter.
  Row pm1 = load_row(ypb, y0 - 1, xl, x0, lane);
  Row pc  = load_row(ypb, y0,     xl, x0, lane);
  Row pp1 = load_row(ypb, y0 + 1, xl, x0, lane);
  Row im1 = load_row(xib, y0 - 1, xl, x0, lane);
  Row icr = load_row(xib, y0,     xl, x0, lane);
  Row ip1 = load_row(xib, y0 + 1, xl, x0, lane);
  float4 w4 = *(const float4*)(wtb + (size_t)y0 * WW + xl);

  for (int y = y0; y < y0 + HSEG; y++) {
    // prefetch two rows ahead (uniform branch: y is wave-uniform)
    Row pn, inx;
    float4 w4n = make_float4(0.f, 0.f, 0.f, 0.f);
    if (y + 2 <= y0 + HSEG) {
      pn  = load_row(ypb, y + 2, xl, x0, lane);
      inx = load_row(xib, y + 2, xl, x0, lane);
    } else {
      pn = zero_row(); inx = zero_row();
    }
    if (y + 1 < y0 + HSEG)
      w4n = *(const float4*)(wtb + (size_t)(y + 1) * WW + xl);

    const float wf[4] = {w4.x, w4.y, w4.z, w4.w};

#pragma unroll
    for (int j = 0; j < 4; j++) {
      const float p00 = LNB(pm1, j), p01 = pm1.f[j], p02 = RNB(pm1, j);
      const float p10 = LNB(pc, j),  p11 = pc.f[j],  p12 = RNB(pc, j);
      const float p20 = LNB(pp1, j), p21 = pp1.f[j], p22 = RNB(pp1, j);
      const float i00 = LNB(im1, j), i01 = im1.f[j], i02 = RNB(im1, j);
      const float i10 = LNB(icr, j), i11 = icr.f[j], i12 = RNB(icr, j);
      const float i20 = LNB(ip1, j), i21 = ip1.f[j], i22 = RNB(ip1, j);

      const float gxp = (p02 - p00) + 2.f * (p12 - p10) + (p22 - p20);
      const float gyp = (p20 - p00) + 2.f * (p21 - p01) + (p22 - p02);
      const float lapp = p01 + p10 + p12 + p21 - 4.f * p11;
      const float gxi_ = (i02 - i00) + 2.f * (i12 - i10) + (i22 - i20);
      const float gyi_ = (i20 - i00) + 2.f * (i21 - i01) + (i22 - i02);
      const float lapi = i01 + i10 + i12 + i21 - 4.f * i11;

      const float yv = p11, xv = i11;
      a_rc += fabsf(yv * wf[j] - xv * wf[j]);

      const bool body = (xv > 0.15f) && (xv < 0.85f);
      if (body) {
        c_body++;
        a_sxi += xv;
        a_syp += yv;
        int bx = (int)(xv * (float)NB);
        bx = bx < 0 ? 0 : (bx > NB - 1 ? NB - 1 : bx);
        int by = (int)(yv * (float)NB);
        by = by < 0 ? 0 : (by > NB - 1 ? NB - 1 : by);
        atomicAdd(&s_hist[bx], 1u);
        atomicAdd(&s_hist[NB + by], 1u);
      }

      a_ex += fabsf(gxp - gxi_);
      a_ey += fabsf(gyp - gyi_);

      const float gmi = sqrtf(gxi_ * gxi_ + gyi_ * gyi_ + 1e-8f);
      const float gmp = sqrtf(gxp * gxp + gyp * gyp + 1e-8f);

      if (gmi > 0.03f && gmi < 0.5f) {
        c_tex++;
        a_tex += fabsf(gmp - gmi);
      }
      const bool flat = gmi < 0.03f;
      if (flat) {
        c_flat++;
        a_hf += fabsf(fabsf(lapp) - 0.3f * fabsf(lapi));
        a_ic += fmaxf(gmp - 2.0f * gmi, 0.f);
      }
      const bool qual = flat && body;
      const unsigned long long m = __ballot(qual);
      if (m) {
        const unsigned bofs = s_fbn[wv];
        if (qual) {
          const unsigned p = bofs + (unsigned)__popcll(m & lmask_lt);
          const unsigned gidx = (unsigned)(base + (size_t)y * WW + (xl + j));
          if (p < FBBUF) {
            s_fb[wv][p] = gidx;
          } else {
            const unsigned gi = atomicAdd(&cnts[3], 1u);
            if ((int)gi < fb_cap) fb_list[gi] = gidx;
          }
        }
        s_fbn[wv] = bofs + (unsigned)__popcll(m);
      }
    }
    pm1 = pc; pc = pp1; pp1 = pn;
    im1 = icr; icr = ip1; ip1 = inx;
    w4 = w4n;
  }

  // flush per-wave fb buffer: ONE global atomic per wave
  {
    unsigned n = s_fbn[wv];
    if (n > FBBUF) n = FBBUF;
    unsigned gbase = 0u;
    if (lane == 0 && n > 0) gbase = atomicAdd(&cnts[3], n);
    gbase = __shfl(gbase, 0, 64);
    for (unsigned i = lane; i < n; i += 64) {
      const unsigned gi = gbase + i;
      if ((int)gi < fb_cap) fb_list[gi] = s_fb[wv][i];
    }
  }

  __syncthreads();
  if (use_parts) {
    // plain coalesced stores; reduce kernel sums them (no atomics)
    unsigned* row = hist_parts + (size_t)blockIdx.x * NHIST;
    for (int i = tid; i < NHIST; i += 256) row[i] = s_hist[i];
  } else {
    for (int i = tid; i < NHIST; i += 256) {
      const unsigned v = s_hist[i];
      if (v) atomicAdd(&hist_final[i], v);
    }
  }

  float f0 = wredf(a_rc), f1 = wredf(a_sxi), f2 = wredf(a_syp);
  float f3 = wredf(a_ex), f4 = wredf(a_ey), f5 = wredf(a_tex);
  float f6 = wredf(a_hf), f7 = wredf(a_ic);
  unsigned u0 = wredu(c_body), u1 = wredu(c_tex), u2 = wredu(c_flat);
  if (lane == 0) {
    s_redf[wv][0] = f0; s_redf[wv][1] = f1; s_redf[wv][2] = f2; s_redf[wv][3] = f3;
    s_redf[wv][4] = f4; s_redf[wv][5] = f5; s_redf[wv][6] = f6; s_redf[wv][7] = f7;
    s_redc[wv][0] = u0; s_redc[wv][1] = u1; s_redc[wv][2] = u2;
  }
  __syncthreads();
  if (tid < 8) {
    double sm = (double)s_redf[0][tid] + (double)s_redf[1][tid] +
                (double)s_redf[2][tid] + (double)s_redf[3][tid];
    atomicAdd(&accs[tid], sm);
  } else if (tid < 11) {
    int k = tid - 8;
    unsigned sm = s_redc[0][k] + s_redc[1][k] + s_redc[2][k] + s_redc[3][k];
    atomicAdd(&cnts[k], sm);
  }
}

__global__ __launch_bounds__(256) void hist_reduce_kernel(
    const unsigned* __restrict__ hist_parts, unsigned* __restrict__ hist_final,
    int nparts) {
  unsigned acc[8];
#pragma unroll
  for (int k = 0; k < 8; k++) acc[k] = 0u;
  for (int p = blockIdx.x; p < nparts; p += gridDim.x) {
    const unsigned* row = hist_parts + (size_t)p * NHIST;
#pragma unroll
    for (int k = 0; k < 8; k++) acc[k] += row[threadIdx.x + k * 256];
  }
#pragma unroll
  for (int k = 0; k < 8; k++)
    if (acc[k]) atomicAdd(&hist_final[threadIdx.x + k * 256], acc[k]);
}

__global__ __launch_bounds__(256) void pass2_kernel(
    const float* __restrict__ yp, const float* __restrict__ xi,
    const float* __restrict__ xm, const float* __restrict__ npred,
    const float* __restrict__ nsyn, double* __restrict__ accs,
    const unsigned* __restrict__ cnts, const unsigned* __restrict__ fb_list,
    int fb_cap) {
  __shared__ float w3[19];
  __shared__ float w1[7];
  __shared__ double s_red[4][3];
  const int tid = threadIdx.x;
  const int lane = tid & 63;
  const int wv = tid >> 6;

  if (tid == 0) {
    float tmp[19], s = 0.f;
    for (int i = 0; i < 19; i++) {
      float c = (float)(i - 9) / 3.0f;
      tmp[i] = expf(-0.5f * c * c);
      s += tmp[i];
    }
    for (int i = 0; i < 19; i++) w3[i] = tmp[i] / s;
    float tmp1[7], s1 = 0.f;
    for (int i = 0; i < 7; i++) {
      float c = (float)(i - 3);
      tmp1[i] = expf(-0.5f * c * c);
      s1 += tmp1[i];
    }
    for (int i = 0; i < 7; i++) w1[i] = tmp1[i] / s1;
  }
  __syncthreads();

  unsigned nfb = cnts[3];
  if (nfb > (unsigned)fb_cap) nfb = (unsigned)fb_cap;
  const int wid = (int)((blockIdx.x * blockDim.x + tid) >> 6);
  const int nwaves = (int)((gridDim.x * blockDim.x) >> 6);

  double w_lf = 0.0, w_md = 0.0, w_sy = 0.0;

  for (int i = wid; i < (int)nfb; i += nwaves) {
    const unsigned px = fb_list[i];
    const int b = (int)(px / (unsigned)HWSZ);
    const int rem = (int)(px % (unsigned)HWSZ);
    const int y = rem / WW;
    const int x = rem % WW;
    const size_t base = (size_t)b * HWSZ;
    const float* xib = xi + base;
    const float* ypb = yp + base;
    const float* xmb = xm + base;

    float npv = 0.f, nsv = 0.f;
    if (lane == 0) { npv = npred[px]; nsv = nsyn[px]; }

    float s_li = 0.f, s_lp = 0.f, s_lm = 0.f;
    float s_gi = 0.f, s_gp = 0.f;
    const bool interior = (y >= 9) && (y < HH - 9) && (x >= 9) && (x < WW - 9);
    if (interior) {
#pragma unroll
      for (int k = 0; k < 6; k++) {
        const int tap = lane + 64 * k;
        if (tap < 361) {
          const int r = tap / 19, c = tap - r * 19;
          const float wgt = w3[r] * w3[c];
          const int o = (y + r - 9) * WW + (x + c - 9);
          s_li += wgt * xib[o];
          s_lp += wgt * ypb[o];
          s_lm += wgt * xmb[o];
        }
      }
      if (lane < 49) {
        const int r = lane / 7, c = lane - r * 7;
        const float wgt = w1[r] * w1[c];
        const int o = (y + r - 3) * WW + (x + c - 3);
        s_gi = wgt * xib[o];
        s_gp = wgt * ypb[o];
      }
    } else {
#pragma unroll
      for (int k = 0; k < 6; k++) {
        const int tap = lane + 64 * k;
        if (tap < 361) {
          const int r = tap / 19, c = tap - r * 19;
          const int gy = y + r - 9, gx = x + c - 9;
          if (gy >= 0 && gy < HH && gx >= 0 && gx < WW) {
            const float wgt = w3[r] * w3[c];
            const int o = gy * WW + gx;
            s_li += wgt * xib[o];
            s_lp += wgt * ypb[o];
            s_lm += wgt * xmb[o];
          }
        }
      }
      if (lane < 49) {
        const int r = lane / 7, c = lane - r * 7;
        const int gy = y + r - 3, gx = x + c - 3;
        if (gy >= 0 && gy < HH && gx >= 0 && gx < WW) {
          const float wgt = w1[r] * w1[c];
          const int o = gy * WW + gx;
          s_gi = wgt * xib[o];
          s_gp = wgt * ypb[o];
        }
      }
    }
    s_li = wredf(s_li);
    s_lp = wredf(s_lp);
    s_lm = wredf(s_lm);
    s_gi = wredf(s_gi);
    s_gp = wredf(s_gp);
    if (lane == 0) {
      const float lf = fabsf((s_lp - s_lm) - 0.3f * (s_li - s_lm));
      const float mi_ = s_gi - s_li, mp_ = s_gp - s_lp;
      const float md = fabsf(fabsf(mp_) - 0.3f * fabsf(mi_));
      w_lf += (double)lf;
      w_md += (double)md;
      w_sy += (double)fabsf(npv - nsv);
    }
  }

  if (lane == 0) {
    s_red[wv][0] = w_lf; s_red[wv][1] = w_md; s_red[wv][2] = w_sy;
  }
  __syncthreads();
  if (tid < 3) {
    const double t = s_red[0][tid] + s_red[1][tid] + s_red[2][tid] + s_red[3][tid];
    if (t != 0.0) atomicAdd(&accs[8 + tid], t);
  }
}

__global__ __launch_bounds__(256) void finalize_kernel(
    const double* __restrict__ accs, const unsigned* __restrict__ cnts,
    const unsigned* __restrict__ hist, float* __restrict__ out) {
  __shared__ unsigned sc[NHIST];
  __shared__ unsigned wsum[8];
  __shared__ double quant[4];
  const int tid = threadIdx.x;
  const int lane = tid & 63;
  const int wv = tid >> 6;

  if (tid < 4) quant[tid] = 0.0;

#pragma unroll
  for (int h = 0; h < 2; h++) {
    const int baseh = h * NB + tid * 4;
    const unsigned v0 = hist[baseh + 0];
    const unsigned v1 = hist[baseh + 1];
    const unsigned v2 = hist[baseh + 2];
    const unsigned v3 = hist[baseh + 3];
    const unsigned s = v0 + v1 + v2 + v3;
    unsigned scl = s;
#pragma unroll
    for (int o = 1; o < 64; o <<= 1) {
      const unsigned t = __shfl_up(scl, o, 64);
      if (lane >= o) scl += t;
    }
    if (lane == 63) wsum[h * 4 + wv] = scl;
    __syncthreads();
    unsigned woff = 0;
    for (int k = 0; k < wv; k++) woff += wsum[h * 4 + k];
    const unsigned excl = woff + scl - s;
    const unsigned c0 = excl + v0;
    const unsigned c1 = c0 + v1;
    const unsigned c2 = c1 + v2;
    const unsigned c3 = c2 + v3;
    sc[baseh + 0] = c0;
    sc[baseh + 1] = c1;
    sc[baseh + 2] = c2;
    sc[baseh + 3] = c3;
    __syncthreads();
  }

  const unsigned nb = cnts[0];
  if (tid < 4 && nb > 4096u) {
    const int h = tid >> 1;
    const double q = (tid & 1) ? 0.75 : 0.25;
    const double pos = q * (double)(nb - 1u);
    int lo = 0, hi = NB - 1;
    while (lo < hi) {
      const int mid = (lo + hi) >> 1;
      if ((double)sc[h * NB + mid] > pos) hi = mid; else lo = mid + 1;
    }
    const unsigned cum_before = (lo > 0) ? sc[h * NB + lo - 1] : 0u;
    const unsigned m = sc[h * NB + lo] - cum_before;
    const double local = pos - (double)cum_before;
    quant[tid] = ((double)lo + (local + 0.5) / (double)(m ? m : 1u)) *
                 (1.0 / (double)NB);
  }
  __syncthreads();
  if (tid != 0) return;

  const unsigned ntex = cnts[1], nflat = cnts[2], nfb = cnts[3];
  const double loss_rc = accs[0] / NPXD;
  const double denb = (double)(nb > 0u ? nb : 1u);
  const double mean_in = accs[1] / denb;
  const double mean_pr = accs[2] / denb;

  double loss_hu = 0.0;
  if (nb > 4096u) {
    const double q25i = quant[0], q75i = quant[1];
    const double q25p = quant[2], q75p = quant[3];
    const double d = mean_pr - mean_in;
    loss_hu = d * d + 0.5 * ((q25p - q25i) * (q25p - q25i) +
                             (q75p - q75i) * (q75p - q75i));
  }

  const double loss_edge = accs[3] / NPXD + accs[4] / NPXD;
  const double loss_tex = (ntex > 100u) ? accs[5] / (double)(ntex ? ntex : 1u) : 0.0;
  const double loss_hf = (nflat > 100u) ? accs[6] / (double)(nflat ? nflat : 1u) : 0.0;
  const double loss_ic = (nflat > 100u) ? accs[7] / (double)(nflat ? nflat : 1u) : 0.0;
  const double denfb = (double)(nfb > 0u ? nfb : 1u);
  const double loss_lf = (nfb > 100u) ? accs[8] / denfb : 0.0;
  const double loss_mid = (nfb > 100u) ? accs[9] / denfb : 0.0;
  const double loss_syn = (nfb > 100u) ? accs[10] / denfb : 0.0;

  const double total = 2.0 * loss_rc + 1.5 * loss_hu + 1.0 * loss_edge +
                       0.8 * loss_tex + 1.5 * loss_hf + 0.8 * loss_mid +
                       0.6 * loss_lf + 1.0 * loss_syn + 0.8 * loss_ic;
  out[0] = (float)total;
}

extern "C" void kernel_launch(void* const* d_in, const int* in_sizes, int n_in,
                              void* d_out, int out_size, void* d_ws,
                              size_t ws_size, hipStream_t stream) {
  (void)in_sizes; (void)n_in; (void)out_size;
  const float* y_pred = (const float*)d_in[0];
  const float* noise_pred = (const float*)d_in[1];
  const float* x_i = (const float*)d_in[2];
  // d_in[3] = x_ip1: unused by the reference
  const float* x_mid = (const float*)d_in[4];
  const float* Wt = (const float*)d_in[5];
  const float* nsyn = (const float*)d_in[6];
  float* out = (float*)d_out;

  char* ws = (char*)d_ws;
  double* accs = (double*)ws;                    // 16 doubles
  unsigned* cnts = (unsigned*)(ws + 128);        // 16 uints
  unsigned* hist_final = (unsigned*)(ws + 256);  // 2048 uints
  const size_t FIXED = 16384;

  const size_t avail = (ws_size > FIXED) ? (ws_size - FIXED) : 0;
  const size_t parts_bytes = (size_t)NBLK1 * NHIST * 4;  // ~12.6 MB
  int use_parts = 0;
  int fb_cap = 0;
  unsigned* fb_list = (unsigned*)(ws + FIXED);
  unsigned* hist_parts = (unsigned*)(ws + FIXED);  // dummy default

  if (avail >= parts_bytes + (1u << 20)) {
    use_parts = 1;
    size_t fb_bytes = avail - parts_bytes;
    if (fb_bytes > (1u << 22)) fb_bytes = (1u << 22);  // 1M entries plenty
    fb_cap = (int)(fb_bytes / 4);
    hist_parts = (unsigned*)(ws + FIXED + fb_bytes);
  } else {
    size_t fb_bytes = avail;
    if (fb_bytes > (1u << 22)) fb_bytes = (1u << 22);
    fb_cap = (int)(fb_bytes / 4);
  }

  hipMemsetAsync(ws, 0, FIXED, stream);
  pass1_kernel<<<NBLK1, 256, 0, stream>>>(y_pred, x_i, Wt, accs, cnts,
                                          fb_list, fb_cap, hist_final,
                                          hist_parts, use_parts);
  if (use_parts)
    hist_reduce_kernel<<<64, 256, 0, stream>>>(hist_parts, hist_final, NBLK1);
  pass2_kernel<<<512, 256, 0, stream>>>(y_pred, x_i, x_mid, noise_pred, nsyn,
                                        accs, cnts, fb_list, fb_cap);
  finalize_kernel<<<1, 256, 0, stream>>>(accs, cnts, hist_final, out);
}

// Round 5
// 276.064 us; speedup vs baseline: 1.6728x; 1.6728x over previous
//
#include <hip/hip_runtime.h>

// HighQualityNSN2NLoss — B=16, H=W=768, fp32, scalar out. x_ip1 unused.
//
// R5: R4's __launch_bounds__(256,5) + deep prefetch caused scratch spills
// (WRITE_SIZE 336 MB, VGPR capped at 48). Revert to the low-pressure
// single-step rolling window; get occupancy from the grid instead:
// HSEG=6 -> 1536 blocks = 6/CU (R3 was grid-limited at 3/CU, occ 27%).

#define HH 768
#define WW 768
#define BB 16
#define HWSZ (HH * WW)
#define NPXD ((double)BB * (double)HWSZ)

#define NB 1024
#define NHIST (2 * NB)

#define STRIPS 3           // 256-wide column strips
#define HSEG 6             // rows per wave-job
#define NSEG (HH / HSEG)   // 128
#define NJOBS (STRIPS * NSEG * BB)  // 6144
#define NBLK1 (NJOBS / 4)           // 1536 blocks (4 waves each) = 6/CU

#define FBBUF 128          // per-wave fb buffer (expected ~2 hits/wave)

__device__ __forceinline__ float wredf(float v) {
#pragma unroll
  for (int o = 32; o > 0; o >>= 1) v += __shfl_down(v, o, 64);
  return v;
}
__device__ __forceinline__ unsigned wredu(unsigned v) {
#pragma unroll
  for (int o = 32; o > 0; o >>= 1) v += __shfl_down(v, o, 64);
  return v;
}

struct Row {
  float f[4];
  float l, r;
};

__device__ __forceinline__ Row load_row(const float* __restrict__ p, int y,
                                        int xl, int x0, int lane) {
  Row r;
  if (y < 0 || y >= HH) {
    r.f[0] = r.f[1] = r.f[2] = r.f[3] = 0.f;
    r.l = 0.f;
    r.r = 0.f;
    return r;
  }
  const float4 v = *(const float4*)(p + (size_t)y * WW + xl);
  r.f[0] = v.x; r.f[1] = v.y; r.f[2] = v.z; r.f[3] = v.w;
  float left = __shfl_up(v.w, 1, 64);
  float right = __shfl_down(v.x, 1, 64);
  if (lane == 0) left = (x0 > 0) ? p[(size_t)y * WW + x0 - 1] : 0.f;
  if (lane == 63) right = (x0 + 256 < WW) ? p[(size_t)y * WW + x0 + 256] : 0.f;
  r.l = left;
  r.r = right;
  return r;
}

#define LNB(row, j) ((j) == 0 ? (row).l : (row).f[(j)-1])
#define RNB(row, j) ((j) == 3 ? (row).r : (row).f[(j) + 1])

// accs: 0 rc, 1 sum_xi_body, 2 sum_yp_body, 3 edge_x, 4 edge_y,
//       5 tex, 6 hf, 7 ic, 8 lf, 9 mid, 10 syn
// cnts: 0 body, 1 tex, 2 flat, 3 fb (append counter)

__global__ __launch_bounds__(256) void pass1_kernel(
    const float* __restrict__ yp, const float* __restrict__ xi,
    const float* __restrict__ wt, double* __restrict__ accs,
    unsigned* __restrict__ cnts, unsigned* __restrict__ fb_list, int fb_cap,
    unsigned* __restrict__ hist_final, unsigned* __restrict__ hist_parts,
    int use_parts) {
  __shared__ unsigned s_hist[NHIST];
  __shared__ unsigned s_fb[4][FBBUF];
  __shared__ unsigned s_fbn[4];
  __shared__ float s_redf[4][8];
  __shared__ unsigned s_redc[4][3];

  const int tid = threadIdx.x;
  const int lane = tid & 63;
  const int wv = tid >> 6;
  const unsigned long long lmask_lt = (1ull << lane) - 1ull;

  for (int i = tid; i < NHIST; i += 256) s_hist[i] = 0u;
  if (lane == 0) s_fbn[wv] = 0u;
  __syncthreads();

  const int job = blockIdx.x * 4 + wv;
  const int s = job % STRIPS;
  const int seg = (job / STRIPS) % NSEG;
  const int b = job / (STRIPS * NSEG);
  const int x0 = s * 256;
  const int y0 = seg * HSEG;
  const int xl = x0 + lane * 4;
  const size_t base = (size_t)b * HWSZ;
  const float* ypb = yp + base;
  const float* xib = xi + base;
  const float* wtb = wt + base;

  float a_rc = 0.f, a_sxi = 0.f, a_syp = 0.f, a_ex = 0.f, a_ey = 0.f;
  float a_tex = 0.f, a_hf = 0.f, a_ic = 0.f;
  unsigned c_body = 0u, c_tex = 0u, c_flat = 0u;

  Row pm1 = load_row(ypb, y0 - 1, xl, x0, lane);
  Row pc = load_row(ypb, y0, xl, x0, lane);
  Row im1 = load_row(xib, y0 - 1, xl, x0, lane);
  Row icr = load_row(xib, y0, xl, x0, lane);

  for (int y = y0; y < y0 + HSEG; y++) {
    const Row pp1 = load_row(ypb, y + 1, xl, x0, lane);
    const Row ip1 = load_row(xib, y + 1, xl, x0, lane);
    const float4 w4 = *(const float4*)(wtb + (size_t)y * WW + xl);
    const float wf[4] = {w4.x, w4.y, w4.z, w4.w};

#pragma unroll
    for (int j = 0; j < 4; j++) {
      const float p00 = LNB(pm1, j), p01 = pm1.f[j], p02 = RNB(pm1, j);
      const float p10 = LNB(pc, j),  p11 = pc.f[j],  p12 = RNB(pc, j);
      const float p20 = LNB(pp1, j), p21 = pp1.f[j], p22 = RNB(pp1, j);
      const float i00 = LNB(im1, j), i01 = im1.f[j], i02 = RNB(im1, j);
      const float i10 = LNB(icr, j), i11 = icr.f[j], i12 = RNB(icr, j);
      const float i20 = LNB(ip1, j), i21 = ip1.f[j], i22 = RNB(ip1, j);

      const float gxp = (p02 - p00) + 2.f * (p12 - p10) + (p22 - p20);
      const float gyp = (p20 - p00) + 2.f * (p21 - p01) + (p22 - p02);
      const float lapp = p01 + p10 + p12 + p21 - 4.f * p11;
      const float gxi_ = (i02 - i00) + 2.f * (i12 - i10) + (i22 - i20);
      const float gyi_ = (i20 - i00) + 2.f * (i21 - i01) + (i22 - i02);
      const float lapi = i01 + i10 + i12 + i21 - 4.f * i11;

      const float yv = p11, xv = i11;
      a_rc += fabsf(yv * wf[j] - xv * wf[j]);

      const bool body = (xv > 0.15f) && (xv < 0.85f);
      if (body) {
        c_body++;
        a_sxi += xv;
        a_syp += yv;
        int bx = (int)(xv * (float)NB);
        bx = bx < 0 ? 0 : (bx > NB - 1 ? NB - 1 : bx);
        int by = (int)(yv * (float)NB);
        by = by < 0 ? 0 : (by > NB - 1 ? NB - 1 : by);
        atomicAdd(&s_hist[bx], 1u);
        atomicAdd(&s_hist[NB + by], 1u);
      }

      a_ex += fabsf(gxp - gxi_);
      a_ey += fabsf(gyp - gyi_);

      const float gmi = sqrtf(gxi_ * gxi_ + gyi_ * gyi_ + 1e-8f);
      const float gmp = sqrtf(gxp * gxp + gyp * gyp + 1e-8f);

      if (gmi > 0.03f && gmi < 0.5f) {
        c_tex++;
        a_tex += fabsf(gmp - gmi);
      }
      const bool flat = gmi < 0.03f;
      if (flat) {
        c_flat++;
        a_hf += fabsf(fabsf(lapp) - 0.3f * fabsf(lapi));
        a_ic += fmaxf(gmp - 2.0f * gmi, 0.f);
      }
      const bool qual = flat && body;
      const unsigned long long m = __ballot(qual);
      if (m) {
        const unsigned bofs = s_fbn[wv];
        if (qual) {
          const unsigned p = bofs + (unsigned)__popcll(m & lmask_lt);
          const unsigned gidx = (unsigned)(base + (size_t)y * WW + (xl + j));
          if (p < FBBUF) {
            s_fb[wv][p] = gidx;
          } else {
            const unsigned gi = atomicAdd(&cnts[3], 1u);
            if ((int)gi < fb_cap) fb_list[gi] = gidx;
          }
        }
        s_fbn[wv] = bofs + (unsigned)__popcll(m);
      }
    }
    pm1 = pc; pc = pp1;
    im1 = icr; icr = ip1;
  }

  // flush per-wave fb buffer: ONE global atomic per wave
  {
    unsigned n = s_fbn[wv];
    if (n > FBBUF) n = FBBUF;
    unsigned gbase = 0u;
    if (lane == 0 && n > 0) gbase = atomicAdd(&cnts[3], n);
    gbase = __shfl(gbase, 0, 64);
    for (unsigned i = lane; i < n; i += 64) {
      const unsigned gi = gbase + i;
      if ((int)gi < fb_cap) fb_list[gi] = s_fb[wv][i];
    }
  }

  __syncthreads();
  if (use_parts) {
    // plain coalesced stores; reduce kernel sums them (no atomics)
    unsigned* row = hist_parts + (size_t)blockIdx.x * NHIST;
    for (int i = tid; i < NHIST; i += 256) row[i] = s_hist[i];
  } else {
    for (int i = tid; i < NHIST; i += 256) {
      const unsigned v = s_hist[i];
      if (v) atomicAdd(&hist_final[i], v);
    }
  }

  float f0 = wredf(a_rc), f1 = wredf(a_sxi), f2 = wredf(a_syp);
  float f3 = wredf(a_ex), f4 = wredf(a_ey), f5 = wredf(a_tex);
  float f6 = wredf(a_hf), f7 = wredf(a_ic);
  unsigned u0 = wredu(c_body), u1 = wredu(c_tex), u2 = wredu(c_flat);
  if (lane == 0) {
    s_redf[wv][0] = f0; s_redf[wv][1] = f1; s_redf[wv][2] = f2; s_redf[wv][3] = f3;
    s_redf[wv][4] = f4; s_redf[wv][5] = f5; s_redf[wv][6] = f6; s_redf[wv][7] = f7;
    s_redc[wv][0] = u0; s_redc[wv][1] = u1; s_redc[wv][2] = u2;
  }
  __syncthreads();
  if (tid < 8) {
    double sm = (double)s_redf[0][tid] + (double)s_redf[1][tid] +
                (double)s_redf[2][tid] + (double)s_redf[3][tid];
    atomicAdd(&accs[tid], sm);
  } else if (tid < 11) {
    int k = tid - 8;
    unsigned sm = s_redc[0][k] + s_redc[1][k] + s_redc[2][k] + s_redc[3][k];
    atomicAdd(&cnts[k], sm);
  }
}

__global__ __launch_bounds__(256) void hist_reduce_kernel(
    const unsigned* __restrict__ hist_parts, unsigned* __restrict__ hist_final,
    int nparts) {
  unsigned acc[8];
#pragma unroll
  for (int k = 0; k < 8; k++) acc[k] = 0u;
  for (int p = blockIdx.x; p < nparts; p += gridDim.x) {
    const unsigned* row = hist_parts + (size_t)p * NHIST;
#pragma unroll
    for (int k = 0; k < 8; k++) acc[k] += row[threadIdx.x + k * 256];
  }
#pragma unroll
  for (int k = 0; k < 8; k++)
    if (acc[k]) atomicAdd(&hist_final[threadIdx.x + k * 256], acc[k]);
}

__global__ __launch_bounds__(256) void pass2_kernel(
    const float* __restrict__ yp, const float* __restrict__ xi,
    const float* __restrict__ xm, const float* __restrict__ npred,
    const float* __restrict__ nsyn, double* __restrict__ accs,
    const unsigned* __restrict__ cnts, const unsigned* __restrict__ fb_list,
    int fb_cap) {
  __shared__ float w3[19];
  __shared__ float w1[7];
  __shared__ double s_red[4][3];
  const int tid = threadIdx.x;
  const int lane = tid & 63;
  const int wv = tid >> 6;

  if (tid == 0) {
    float tmp[19], s = 0.f;
    for (int i = 0; i < 19; i++) {
      float c = (float)(i - 9) / 3.0f;
      tmp[i] = expf(-0.5f * c * c);
      s += tmp[i];
    }
    for (int i = 0; i < 19; i++) w3[i] = tmp[i] / s;
    float tmp1[7], s1 = 0.f;
    for (int i = 0; i < 7; i++) {
      float c = (float)(i - 3);
      tmp1[i] = expf(-0.5f * c * c);
      s1 += tmp1[i];
    }
    for (int i = 0; i < 7; i++) w1[i] = tmp1[i] / s1;
  }
  __syncthreads();

  unsigned nfb = cnts[3];
  if (nfb > (unsigned)fb_cap) nfb = (unsigned)fb_cap;
  const int wid = (int)((blockIdx.x * blockDim.x + tid) >> 6);
  const int nwaves = (int)((gridDim.x * blockDim.x) >> 6);

  double w_lf = 0.0, w_md = 0.0, w_sy = 0.0;

  for (int i = wid; i < (int)nfb; i += nwaves) {
    const unsigned px = fb_list[i];
    const int b = (int)(px / (unsigned)HWSZ);
    const int rem = (int)(px % (unsigned)HWSZ);
    const int y = rem / WW;
    const int x = rem % WW;
    const size_t base = (size_t)b * HWSZ;
    const float* xib = xi + base;
    const float* ypb = yp + base;
    const float* xmb = xm + base;

    float npv = 0.f, nsv = 0.f;
    if (lane == 0) { npv = npred[px]; nsv = nsyn[px]; }

    float s_li = 0.f, s_lp = 0.f, s_lm = 0.f;
    float s_gi = 0.f, s_gp = 0.f;
    const bool interior = (y >= 9) && (y < HH - 9) && (x >= 9) && (x < WW - 9);
    if (interior) {
#pragma unroll
      for (int k = 0; k < 6; k++) {
        const int tap = lane + 64 * k;
        if (tap < 361) {
          const int r = tap / 19, c = tap - r * 19;
          const float wgt = w3[r] * w3[c];
          const int o = (y + r - 9) * WW + (x + c - 9);
          s_li += wgt * xib[o];
          s_lp += wgt * ypb[o];
          s_lm += wgt * xmb[o];
        }
      }
      if (lane < 49) {
        const int r = lane / 7, c = lane - r * 7;
        const float wgt = w1[r] * w1[c];
        const int o = (y + r - 3) * WW + (x + c - 3);
        s_gi = wgt * xib[o];
        s_gp = wgt * ypb[o];
      }
    } else {
#pragma unroll
      for (int k = 0; k < 6; k++) {
        const int tap = lane + 64 * k;
        if (tap < 361) {
          const int r = tap / 19, c = tap - r * 19;
          const int gy = y + r - 9, gx = x + c - 9;
          if (gy >= 0 && gy < HH && gx >= 0 && gx < WW) {
            const float wgt = w3[r] * w3[c];
            const int o = gy * WW + gx;
            s_li += wgt * xib[o];
            s_lp += wgt * ypb[o];
            s_lm += wgt * xmb[o];
          }
        }
      }
      if (lane < 49) {
        const int r = lane / 7, c = lane - r * 7;
        const int gy = y + r - 3, gx = x + c - 3;
        if (gy >= 0 && gy < HH && gx >= 0 && gx < WW) {
          const float wgt = w1[r] * w1[c];
          const int o = gy * WW + gx;
          s_gi = wgt * xib[o];
          s_gp = wgt * ypb[o];
        }
      }
    }
    s_li = wredf(s_li);
    s_lp = wredf(s_lp);
    s_lm = wredf(s_lm);
    s_gi = wredf(s_gi);
    s_gp = wredf(s_gp);
    if (lane == 0) {
      const float lf = fabsf((s_lp - s_lm) - 0.3f * (s_li - s_lm));
      const float mi_ = s_gi - s_li, mp_ = s_gp - s_lp;
      const float md = fabsf(fabsf(mp_) - 0.3f * fabsf(mi_));
      w_lf += (double)lf;
      w_md += (double)md;
      w_sy += (double)fabsf(npv - nsv);
    }
  }

  if (lane == 0) {
    s_red[wv][0] = w_lf; s_red[wv][1] = w_md; s_red[wv][2] = w_sy;
  }
  __syncthreads();
  if (tid < 3) {
    const double t = s_red[0][tid] + s_red[1][tid] + s_red[2][tid] + s_red[3][tid];
    if (t != 0.0) atomicAdd(&accs[8 + tid], t);
  }
}

__global__ __launch_bounds__(256) void finalize_kernel(
    const double* __restrict__ accs, const unsigned* __restrict__ cnts,
    const unsigned* __restrict__ hist, float* __restrict__ out) {
  __shared__ unsigned sc[NHIST];
  __shared__ unsigned wsum[8];
  __shared__ double quant[4];
  const int tid = threadIdx.x;
  const int lane = tid & 63;
  const int wv = tid >> 6;

  if (tid < 4) quant[tid] = 0.0;

#pragma unroll
  for (int h = 0; h < 2; h++) {
    const int baseh = h * NB + tid * 4;
    const unsigned v0 = hist[baseh + 0];
    const unsigned v1 = hist[baseh + 1];
    const unsigned v2 = hist[baseh + 2];
    const unsigned v3 = hist[baseh + 3];
    const unsigned s = v0 + v1 + v2 + v3;
    unsigned scl = s;
#pragma unroll
    for (int o = 1; o < 64; o <<= 1) {
      const unsigned t = __shfl_up(scl, o, 64);
      if (lane >= o) scl += t;
    }
    if (lane == 63) wsum[h * 4 + wv] = scl;
    __syncthreads();
    unsigned woff = 0;
    for (int k = 0; k < wv; k++) woff += wsum[h * 4 + k];
    const unsigned excl = woff + scl - s;
    const unsigned c0 = excl + v0;
    const unsigned c1 = c0 + v1;
    const unsigned c2 = c1 + v2;
    const unsigned c3 = c2 + v3;
    sc[baseh + 0] = c0;
    sc[baseh + 1] = c1;
    sc[baseh + 2] = c2;
    sc[baseh + 3] = c3;
    __syncthreads();
  }

  const unsigned nb = cnts[0];
  if (tid < 4 && nb > 4096u) {
    const int h = tid >> 1;
    const double q = (tid & 1) ? 0.75 : 0.25;
    const double pos = q * (double)(nb - 1u);
    int lo = 0, hi = NB - 1;
    while (lo < hi) {
      const int mid = (lo + hi) >> 1;
      if ((double)sc[h * NB + mid] > pos) hi = mid; else lo = mid + 1;
    }
    const unsigned cum_before = (lo > 0) ? sc[h * NB + lo - 1] : 0u;
    const unsigned m = sc[h * NB + lo] - cum_before;
    const double local = pos - (double)cum_before;
    quant[tid] = ((double)lo + (local + 0.5) / (double)(m ? m : 1u)) *
                 (1.0 / (double)NB);
  }
  __syncthreads();
  if (tid != 0) return;

  const unsigned ntex = cnts[1], nflat = cnts[2], nfb = cnts[3];
  const double loss_rc = accs[0] / NPXD;
  const double denb = (double)(nb > 0u ? nb : 1u);
  const double mean_in = accs[1] / denb;
  const double mean_pr = accs[2] / denb;

  double loss_hu = 0.0;
  if (nb > 4096u) {
    const double q25i = quant[0], q75i = quant[1];
    const double q25p = quant[2], q75p = quant[3];
    const double d = mean_pr - mean_in;
    loss_hu = d * d + 0.5 * ((q25p - q25i) * (q25p - q25i) +
                             (q75p - q75i) * (q75p - q75i));
  }

  const double loss_edge = accs[3] / NPXD + accs[4] / NPXD;
  const double loss_tex = (ntex > 100u) ? accs[5] / (double)(ntex ? ntex : 1u) : 0.0;
  const double loss_hf = (nflat > 100u) ? accs[6] / (double)(nflat ? nflat : 1u) : 0.0;
  const double loss_ic = (nflat > 100u) ? accs[7] / (double)(nflat ? nflat : 1u) : 0.0;
  const double denfb = (double)(nfb > 0u ? nfb : 1u);
  const double loss_lf = (nfb > 100u) ? accs[8] / denfb : 0.0;
  const double loss_mid = (nfb > 100u) ? accs[9] / denfb : 0.0;
  const double loss_syn = (nfb > 100u) ? accs[10] / denfb : 0.0;

  const double total = 2.0 * loss_rc + 1.5 * loss_hu + 1.0 * loss_edge +
                       0.8 * loss_tex + 1.5 * loss_hf + 0.8 * loss_mid +
                       0.6 * loss_lf + 1.0 * loss_syn + 0.8 * loss_ic;
  out[0] = (float)total;
}

extern "C" void kernel_launch(void* const* d_in, const int* in_sizes, int n_in,
                              void* d_out, int out_size, void* d_ws,
                              size_t ws_size, hipStream_t stream) {
  (void)in_sizes; (void)n_in; (void)out_size;
  const float* y_pred = (const float*)d_in[0];
  const float* noise_pred = (const float*)d_in[1];
  const float* x_i = (const float*)d_in[2];
  // d_in[3] = x_ip1: unused by the reference
  const float* x_mid = (const float*)d_in[4];
  const float* Wt = (const float*)d_in[5];
  const float* nsyn = (const float*)d_in[6];
  float* out = (float*)d_out;

  char* ws = (char*)d_ws;
  double* accs = (double*)ws;                    // 16 doubles
  unsigned* cnts = (unsigned*)(ws + 128);        // 16 uints
  unsigned* hist_final = (unsigned*)(ws + 256);  // 2048 uints
  const size_t FIXED = 16384;

  const size_t avail = (ws_size > FIXED) ? (ws_size - FIXED) : 0;
  const size_t parts_bytes = (size_t)NBLK1 * NHIST * 4;  // ~12.6 MB
  int use_parts = 0;
  int fb_cap = 0;
  unsigned* fb_list = (unsigned*)(ws + FIXED);
  unsigned* hist_parts = (unsigned*)(ws + FIXED);  // dummy default

  if (avail >= parts_bytes + (1u << 20)) {
    use_parts = 1;
    size_t fb_bytes = avail - parts_bytes;
    if (fb_bytes > (1u << 22)) fb_bytes = (1u << 22);  // 1M entries plenty
    fb_cap = (int)(fb_bytes / 4);
    hist_parts = (unsigned*)(ws + FIXED + fb_bytes);
  } else {
    size_t fb_bytes = avail;
    if (fb_bytes > (1u << 22)) fb_bytes = (1u << 22);
    fb_cap = (int)(fb_bytes / 4);
  }

  hipMemsetAsync(ws, 0, FIXED, stream);
  pass1_kernel<<<NBLK1, 256, 0, stream>>>(y_pred, x_i, Wt, accs, cnts,
                                          fb_list, fb_cap, hist_final,
                                          hist_parts, use_parts);
  if (use_parts)
    hist_reduce_kernel<<<64, 256, 0, stream>>>(hist_parts, hist_final, NBLK1);
  pass2_kernel<<<512, 256, 0, stream>>>(y_pred, x_i, x_mid, noise_pred, nsyn,
                                        accs, cnts, fb_list, fb_cap);
  finalize_kernel<<<1, 256, 0, stream>>>(accs, cnts, hist_final, out);
}